// Round 1
// baseline (2111.208 us; speedup 1.0000x reference)
//
#include <hip/hip_runtime.h>

// GNN: 2x SAGEConv(sum) + global_add_pool + Linear head.
// N=50000 nodes, E=1e6 edges, D=H=64, G=512 graphs, O=16.
// Baseline strategy: atomic scatter-add for edge aggregation (the expected
// bottleneck), fused fp32 GEMM+ReLU kernels with weights in LDS, pooling
// fused into layer-2 epilogue (h2 never hits memory).

namespace {
constexpr int NN = 50000;
constexpr int NE = 1000000;
constexpr int NG = 512;
constexpr int NO = 16;
}

// One edge handled by 16 threads: float4 gather from feat[src], 4 atomic
// adds into agg[dst]. Edge index loads broadcast across the 16 threads (L1).
__global__ __launch_bounds__(256) void scatter_add64(
    const float* __restrict__ feat, const int* __restrict__ ei,
    float* __restrict__ agg) {
  int gid = blockIdx.x * 256 + threadIdx.x;
  int e = gid >> 4;
  int q = gid & 15;
  if (e >= NE) return;
  int src = ei[e];
  int dst = ei[NE + e];
  float4 v = *reinterpret_cast<const float4*>(feat + (size_t)src * 64 + q * 4);
  float* d = agg + (size_t)dst * 64 + q * 4;
  atomicAdd(d + 0, v.x);
  atomicAdd(d + 1, v.y);
  atomicAdd(d + 2, v.z);
  atomicAdd(d + 3, v.w);
}

// out[row,:] = relu(A[row,:] @ Wl + Hr[row,:] @ Wr + b)
// Block = 256 threads = 64 rows x 4 col-chunks of 16. Weights in LDS (32 KB).
// LDS reads broadcast (4 distinct addresses per wave) -> conflict-free.
__global__ __launch_bounds__(256) void sage_lin_relu(
    const float* __restrict__ A, const float* __restrict__ Hr,
    const float* __restrict__ Wl, const float* __restrict__ Wr,
    const float* __restrict__ bias, float* __restrict__ out) {
  __shared__ float sWl[64 * 64];
  __shared__ float sWr[64 * 64];
  int tid = threadIdx.x;
#pragma unroll
  for (int i = 0; i < 4; ++i) {
    int idx = i * 1024 + tid * 4;
    *reinterpret_cast<float4*>(sWl + idx) =
        *reinterpret_cast<const float4*>(Wl + idx);
    *reinterpret_cast<float4*>(sWr + idx) =
        *reinterpret_cast<const float4*>(Wr + idx);
  }
  __syncthreads();
  int r = tid >> 2, c = tid & 3;
  long row = (long)blockIdx.x * 64 + r;
  if (row >= NN) return;
  const float4* A4 = reinterpret_cast<const float4*>(A + row * 64);
  const float4* H4 = reinterpret_cast<const float4*>(Hr + row * 64);
  float acc[16];
#pragma unroll
  for (int j = 0; j < 16; ++j) acc[j] = bias[c * 16 + j];
#pragma unroll 4
  for (int k4 = 0; k4 < 16; ++k4) {
    float4 a4 = A4[k4];
    float4 h4 = H4[k4];
    float av[4] = {a4.x, a4.y, a4.z, a4.w};
    float hv[4] = {h4.x, h4.y, h4.z, h4.w};
    const float* wl = sWl + k4 * 4 * 64 + c * 16;
    const float* wr = sWr + k4 * 4 * 64 + c * 16;
#pragma unroll
    for (int kk = 0; kk < 4; ++kk) {
#pragma unroll
      for (int j = 0; j < 16; ++j) {
        acc[j] += av[kk] * wl[kk * 64 + j] + hv[kk] * wr[kk * 64 + j];
      }
    }
  }
  float* o = out + row * 64 + c * 16;
#pragma unroll
  for (int j = 0; j < 16; ++j) o[j] = fmaxf(acc[j], 0.0f);
}

// Same GEMM, but epilogue pools relu(h2) into pooled[batch[row]] atomically.
__global__ __launch_bounds__(256) void sage_lin_relu_pool(
    const float* __restrict__ A, const float* __restrict__ Hr,
    const float* __restrict__ Wl, const float* __restrict__ Wr,
    const float* __restrict__ bias, const int* __restrict__ batch,
    float* __restrict__ pooled) {
  __shared__ float sWl[64 * 64];
  __shared__ float sWr[64 * 64];
  int tid = threadIdx.x;
#pragma unroll
  for (int i = 0; i < 4; ++i) {
    int idx = i * 1024 + tid * 4;
    *reinterpret_cast<float4*>(sWl + idx) =
        *reinterpret_cast<const float4*>(Wl + idx);
    *reinterpret_cast<float4*>(sWr + idx) =
        *reinterpret_cast<const float4*>(Wr + idx);
  }
  __syncthreads();
  int r = tid >> 2, c = tid & 3;
  long row = (long)blockIdx.x * 64 + r;
  if (row >= NN) return;
  const float4* A4 = reinterpret_cast<const float4*>(A + row * 64);
  const float4* H4 = reinterpret_cast<const float4*>(Hr + row * 64);
  float acc[16];
#pragma unroll
  for (int j = 0; j < 16; ++j) acc[j] = bias[c * 16 + j];
#pragma unroll 4
  for (int k4 = 0; k4 < 16; ++k4) {
    float4 a4 = A4[k4];
    float4 h4 = H4[k4];
    float av[4] = {a4.x, a4.y, a4.z, a4.w};
    float hv[4] = {h4.x, h4.y, h4.z, h4.w};
    const float* wl = sWl + k4 * 4 * 64 + c * 16;
    const float* wr = sWr + k4 * 4 * 64 + c * 16;
#pragma unroll
    for (int kk = 0; kk < 4; ++kk) {
#pragma unroll
      for (int j = 0; j < 16; ++j) {
        acc[j] += av[kk] * wl[kk * 64 + j] + hv[kk] * wr[kk * 64 + j];
      }
    }
  }
  int g = batch[row];
  float* p = pooled + (size_t)g * 64 + c * 16;
#pragma unroll
  for (int j = 0; j < 16; ++j) atomicAdd(p + j, fmaxf(acc[j], 0.0f));
}

// out[g,o] = pooled[g,:] @ Wo[:,o] + bo[o]   (512x16, trivial)
__global__ __launch_bounds__(256) void head_kernel(
    const float* __restrict__ pooled, const float* __restrict__ Wo,
    const float* __restrict__ bo, float* __restrict__ out) {
  int gid = blockIdx.x * 256 + threadIdx.x;
  if (gid >= NG * NO) return;
  int g = gid >> 4, o = gid & 15;
  float acc = bo[o];
  const float* p = pooled + (size_t)g * 64;
#pragma unroll
  for (int k = 0; k < 64; ++k) acc += p[k] * Wo[k * 16 + o];
  out[gid] = acc;
}

extern "C" void kernel_launch(void* const* d_in, const int* in_sizes, int n_in,
                              void* d_out, int out_size, void* d_ws,
                              size_t ws_size, hipStream_t stream) {
  const float* x = (const float*)d_in[0];
  const int* ei = (const int*)d_in[1];
  const int* batch = (const int*)d_in[2];
  const float* Wl1 = (const float*)d_in[3];
  const float* Wr1 = (const float*)d_in[4];
  const float* b1 = (const float*)d_in[5];
  const float* Wl2 = (const float*)d_in[6];
  const float* Wr2 = (const float*)d_in[7];
  const float* b2 = (const float*)d_in[8];
  const float* Wo = (const float*)d_in[9];
  const float* bo = (const float*)d_in[10];
  float* out = (float*)d_out;

  // Workspace layout (all fp32): agg[N*64] | h1[N*64] | pooled[G*64]
  float* agg = (float*)d_ws;
  float* h1 = agg + (size_t)NN * 64;
  float* pooled = h1 + (size_t)NN * 64;

  hipMemsetAsync(agg, 0, (size_t)NN * 64 * sizeof(float), stream);
  hipMemsetAsync(pooled, 0, (size_t)NG * 64 * sizeof(float), stream);

  const int scatter_blocks = (NE * 16 + 255) / 256;  // 62500
  const int gemm_blocks = (NN + 63) / 64;            // 782

  // Layer 1
  scatter_add64<<<scatter_blocks, 256, 0, stream>>>(x, ei, agg);
  sage_lin_relu<<<gemm_blocks, 256, 0, stream>>>(agg, x, Wl1, Wr1, b1, h1);

  // Layer 2 (re-zero agg, aggregate h1, fuse pooling into epilogue)
  hipMemsetAsync(agg, 0, (size_t)NN * 64 * sizeof(float), stream);
  scatter_add64<<<scatter_blocks, 256, 0, stream>>>(h1, ei, agg);
  sage_lin_relu_pool<<<gemm_blocks, 256, 0, stream>>>(agg, h1, Wl2, Wr2, b2,
                                                      batch, pooled);

  // Head
  head_kernel<<<(NG * NO + 255) / 256, 256, 0, stream>>>(pooled, Wo, bo, out);
}

// Round 2
// 605.731 us; speedup vs baseline: 3.4854x; 3.4854x over previous
//
#include <hip/hip_runtime.h>

// GNN: 2x SAGEConv(sum) + global_add_pool + Linear head.
// N=50000 nodes, E=1e6 edges, D=H=64, G=512 graphs, O=16.
//
// R1: scatter-atomic aggregation (75 G atomics/s TCC ceiling, 849 us/layer)
// replaced by device-built CSR (by dst) + pure-gather aggregation.
// CSR build: histogram -> 3-kernel block scan -> atomic placement (~1.1M int
// atomics once) vs 128M fp32 atomics before.

namespace {
constexpr int NN = 50000;
constexpr int NE = 1000000;
constexpr int NG = 512;
constexpr int NO = 16;
constexpr int CHUNK = 1024;
constexpr int NB = (NN + CHUNK - 1) / CHUNK;  // 49 scan blocks
}

// ---------------- CSR build ----------------

__global__ __launch_bounds__(256) void hist_kernel(const int* __restrict__ ei,
                                                   int* __restrict__ deg) {
  int e = blockIdx.x * 256 + threadIdx.x;
  if (e < NE) atomicAdd(&deg[ei[NE + e]], 1);
}

// Per-chunk sums of deg -> bsum[NB]
__global__ __launch_bounds__(CHUNK) void chunk_sum_kernel(
    const int* __restrict__ deg, int* __restrict__ bsum) {
  __shared__ int sm[CHUNK];
  int i = blockIdx.x * CHUNK + threadIdx.x;
  sm[threadIdx.x] = (i < NN) ? deg[i] : 0;
  __syncthreads();
  for (int off = CHUNK / 2; off > 0; off >>= 1) {
    if (threadIdx.x < off) sm[threadIdx.x] += sm[threadIdx.x + off];
    __syncthreads();
  }
  if (threadIdx.x == 0) bsum[blockIdx.x] = sm[0];
}

// Exclusive scan of bsum (tiny: NB=49) -> boff[NB]
__global__ __launch_bounds__(64) void scan_bsum_kernel(
    const int* __restrict__ bsum, int* __restrict__ boff) {
  if (threadIdx.x == 0) {
    int run = 0;
    for (int b = 0; b < NB; ++b) {
      boff[b] = run;
      run += bsum[b];
    }
  }
}

// Per-chunk exclusive scan + chunk offset -> row_ptr, cursor
__global__ __launch_bounds__(CHUNK) void emit_rowptr_kernel(
    const int* __restrict__ deg, const int* __restrict__ boff,
    int* __restrict__ row_ptr, int* __restrict__ cursor) {
  __shared__ int sm[CHUNK];
  int i = blockIdx.x * CHUNK + threadIdx.x;
  int v = (i < NN) ? deg[i] : 0;
  sm[threadIdx.x] = v;
  __syncthreads();
  // Hillis-Steele inclusive scan
  for (int off = 1; off < CHUNK; off <<= 1) {
    int t = (threadIdx.x >= off) ? sm[threadIdx.x - off] : 0;
    __syncthreads();
    sm[threadIdx.x] += t;
    __syncthreads();
  }
  int excl = sm[threadIdx.x] - v;
  if (i < NN) {
    int val = boff[blockIdx.x] + excl;
    row_ptr[i] = val;
    cursor[i] = val;
  }
  if (blockIdx.x == 0 && threadIdx.x == 0) row_ptr[NN] = NE;  // total edges
}

// col[pos] = src for each edge, pos allocated via cursor atomics.
__global__ __launch_bounds__(256) void place_kernel(const int* __restrict__ ei,
                                                    int* __restrict__ cursor,
                                                    int* __restrict__ col) {
  int e = blockIdx.x * 256 + threadIdx.x;
  if (e >= NE) return;
  int src = ei[e];
  int dst = ei[NE + e];
  int pos = atomicAdd(&cursor[dst], 1);
  col[pos] = src;
}

// ---------------- aggregation (gather, no atomics) ----------------
// 16 threads per node, float4 per thread. col[j] broadcast-loaded by the 16
// threads (L1); feat rows are 256B coalesced segments (LLC-resident, 12.8MB).
__global__ __launch_bounds__(256) void gather_csr(
    const float* __restrict__ feat, const int* __restrict__ row_ptr,
    const int* __restrict__ col, float* __restrict__ agg) {
  int gid = blockIdx.x * 256 + threadIdx.x;
  int v = gid >> 4;
  int q = gid & 15;
  if (v >= NN) return;
  int beg = row_ptr[v], end = row_ptr[v + 1];
  float4 acc = {0.f, 0.f, 0.f, 0.f};
  for (int j = beg; j < end; ++j) {
    int s = col[j];
    float4 f = *reinterpret_cast<const float4*>(feat + (size_t)s * 64 + q * 4);
    acc.x += f.x;
    acc.y += f.y;
    acc.z += f.z;
    acc.w += f.w;
  }
  *reinterpret_cast<float4*>(agg + (size_t)v * 64 + q * 4) = acc;
}

// ---------------- fused GEMMs ----------------
// out[row,:] = relu(A[row,:] @ Wl + Hr[row,:] @ Wr + b)
// Block = 256 threads = 64 rows x 4 col-chunks of 16. Weights in LDS (32 KB).
__global__ __launch_bounds__(256) void sage_lin_relu(
    const float* __restrict__ A, const float* __restrict__ Hr,
    const float* __restrict__ Wl, const float* __restrict__ Wr,
    const float* __restrict__ bias, float* __restrict__ out) {
  __shared__ float sWl[64 * 64];
  __shared__ float sWr[64 * 64];
  int tid = threadIdx.x;
#pragma unroll
  for (int i = 0; i < 4; ++i) {
    int idx = i * 1024 + tid * 4;
    *reinterpret_cast<float4*>(sWl + idx) =
        *reinterpret_cast<const float4*>(Wl + idx);
    *reinterpret_cast<float4*>(sWr + idx) =
        *reinterpret_cast<const float4*>(Wr + idx);
  }
  __syncthreads();
  int r = tid >> 2, c = tid & 3;
  long row = (long)blockIdx.x * 64 + r;
  if (row >= NN) return;
  const float4* A4 = reinterpret_cast<const float4*>(A + row * 64);
  const float4* H4 = reinterpret_cast<const float4*>(Hr + row * 64);
  float acc[16];
#pragma unroll
  for (int j = 0; j < 16; ++j) acc[j] = bias[c * 16 + j];
#pragma unroll 4
  for (int k4 = 0; k4 < 16; ++k4) {
    float4 a4 = A4[k4];
    float4 h4 = H4[k4];
    float av[4] = {a4.x, a4.y, a4.z, a4.w};
    float hv[4] = {h4.x, h4.y, h4.z, h4.w};
    const float* wl = sWl + k4 * 4 * 64 + c * 16;
    const float* wr = sWr + k4 * 4 * 64 + c * 16;
#pragma unroll
    for (int kk = 0; kk < 4; ++kk) {
#pragma unroll
      for (int j = 0; j < 16; ++j) {
        acc[j] += av[kk] * wl[kk * 64 + j] + hv[kk] * wr[kk * 64 + j];
      }
    }
  }
  float* o = out + row * 64 + c * 16;
#pragma unroll
  for (int j = 0; j < 16; ++j) o[j] = fmaxf(acc[j], 0.0f);
}

// Same GEMM, epilogue pools relu(h2) into pooled[batch[row]] atomically.
__global__ __launch_bounds__(256) void sage_lin_relu_pool(
    const float* __restrict__ A, const float* __restrict__ Hr,
    const float* __restrict__ Wl, const float* __restrict__ Wr,
    const float* __restrict__ bias, const int* __restrict__ batch,
    float* __restrict__ pooled) {
  __shared__ float sWl[64 * 64];
  __shared__ float sWr[64 * 64];
  int tid = threadIdx.x;
#pragma unroll
  for (int i = 0; i < 4; ++i) {
    int idx = i * 1024 + tid * 4;
    *reinterpret_cast<float4*>(sWl + idx) =
        *reinterpret_cast<const float4*>(Wl + idx);
    *reinterpret_cast<float4*>(sWr + idx) =
        *reinterpret_cast<const float4*>(Wr + idx);
  }
  __syncthreads();
  int r = tid >> 2, c = tid & 3;
  long row = (long)blockIdx.x * 64 + r;
  if (row >= NN) return;
  const float4* A4 = reinterpret_cast<const float4*>(A + row * 64);
  const float4* H4 = reinterpret_cast<const float4*>(Hr + row * 64);
  float acc[16];
#pragma unroll
  for (int j = 0; j < 16; ++j) acc[j] = bias[c * 16 + j];
#pragma unroll 4
  for (int k4 = 0; k4 < 16; ++k4) {
    float4 a4 = A4[k4];
    float4 h4 = H4[k4];
    float av[4] = {a4.x, a4.y, a4.z, a4.w};
    float hv[4] = {h4.x, h4.y, h4.z, h4.w};
    const float* wl = sWl + k4 * 4 * 64 + c * 16;
    const float* wr = sWr + k4 * 4 * 64 + c * 16;
#pragma unroll
    for (int kk = 0; kk < 4; ++kk) {
#pragma unroll
      for (int j = 0; j < 16; ++j) {
        acc[j] += av[kk] * wl[kk * 64 + j] + hv[kk] * wr[kk * 64 + j];
      }
    }
  }
  int g = batch[row];
  float* p = pooled + (size_t)g * 64 + c * 16;
#pragma unroll
  for (int j = 0; j < 16; ++j) atomicAdd(p + j, fmaxf(acc[j], 0.0f));
}

// out[g,o] = pooled[g,:] @ Wo[:,o] + bo[o]
__global__ __launch_bounds__(256) void head_kernel(
    const float* __restrict__ pooled, const float* __restrict__ Wo,
    const float* __restrict__ bo, float* __restrict__ out) {
  int gid = blockIdx.x * 256 + threadIdx.x;
  if (gid >= NG * NO) return;
  int g = gid >> 4, o = gid & 15;
  float acc = bo[o];
  const float* p = pooled + (size_t)g * 64;
#pragma unroll
  for (int k = 0; k < 64; ++k) acc += p[k] * Wo[k * 16 + o];
  out[gid] = acc;
}

extern "C" void kernel_launch(void* const* d_in, const int* in_sizes, int n_in,
                              void* d_out, int out_size, void* d_ws,
                              size_t ws_size, hipStream_t stream) {
  const float* x = (const float*)d_in[0];
  const int* ei = (const int*)d_in[1];
  const int* batch = (const int*)d_in[2];
  const float* Wl1 = (const float*)d_in[3];
  const float* Wr1 = (const float*)d_in[4];
  const float* b1 = (const float*)d_in[5];
  const float* Wl2 = (const float*)d_in[6];
  const float* Wr2 = (const float*)d_in[7];
  const float* b2 = (const float*)d_in[8];
  const float* Wo = (const float*)d_in[9];
  const float* bo = (const float*)d_in[10];
  float* out = (float*)d_out;

  // Workspace layout: ints first, then floats.
  int* deg = (int*)d_ws;              // NN
  int* row_ptr = deg + NN;            // NN+1
  int* cursor = row_ptr + NN + 1;     // NN
  int* bsum = cursor + NN;            // NB
  int* boff = bsum + NB;              // NB
  int* col = boff + NB;               // NE
  float* agg = (float*)(col + NE);    // NN*64
  float* h1 = agg + (size_t)NN * 64;  // NN*64
  float* pooled = h1 + (size_t)NN * 64;  // NG*64

  hipMemsetAsync(deg, 0, (size_t)NN * sizeof(int), stream);
  hipMemsetAsync(pooled, 0, (size_t)NG * 64 * sizeof(float), stream);

  const int eblocks = (NE + 255) / 256;
  const int gather_blocks = (NN * 16 + 255) / 256;
  const int gemm_blocks = (NN + 63) / 64;

  // CSR build (once; reused by both layers)
  hist_kernel<<<eblocks, 256, 0, stream>>>(ei, deg);
  chunk_sum_kernel<<<NB, CHUNK, 0, stream>>>(deg, bsum);
  scan_bsum_kernel<<<1, 64, 0, stream>>>(bsum, boff);
  emit_rowptr_kernel<<<NB, CHUNK, 0, stream>>>(deg, boff, row_ptr, cursor);
  place_kernel<<<eblocks, 256, 0, stream>>>(ei, cursor, col);

  // Layer 1
  gather_csr<<<gather_blocks, 256, 0, stream>>>(x, row_ptr, col, agg);
  sage_lin_relu<<<gemm_blocks, 256, 0, stream>>>(agg, x, Wl1, Wr1, b1, h1);

  // Layer 2 (pooling fused into epilogue)
  gather_csr<<<gather_blocks, 256, 0, stream>>>(h1, row_ptr, col, agg);
  sage_lin_relu_pool<<<gemm_blocks, 256, 0, stream>>>(agg, h1, Wl2, Wr2, b2,
                                                      batch, pooled);

  // Head
  head_kernel<<<(NG * NO + 255) / 256, 256, 0, stream>>>(pooled, Wo, bo, out);
}

// Round 3
// 394.603 us; speedup vs baseline: 5.3502x; 1.5350x over previous
//
#include <hip/hip_runtime.h>

// GNN: 2x SAGEConv(sum) + global_add_pool + Linear head.
// N=50000 nodes, E=1e6 edges, D=H=64, G=512 graphs, O=16.
//
// R1: CSR gather replaced scatter atomics (2111 -> 606 us).
// R2: atomic pooling (290 us: 3.2M same-address atomics, batch is SORTED)
// replaced by segmented reduction: binary-search graph boundaries, one
// block per graph sums its contiguous row range, head GEMV fused in.
// Layer-2 GEMM writes in-place into agg (no extra workspace).

namespace {
constexpr int NN = 50000;
constexpr int NE = 1000000;
constexpr int NG = 512;
constexpr int NO = 16;
constexpr int CHUNK = 1024;
constexpr int NB = (NN + CHUNK - 1) / CHUNK;  // 49 scan blocks
}

// ---------------- CSR build ----------------

__global__ __launch_bounds__(256) void hist_kernel(const int* __restrict__ ei,
                                                   int* __restrict__ deg) {
  int e = blockIdx.x * 256 + threadIdx.x;
  if (e < NE) atomicAdd(&deg[ei[NE + e]], 1);
}

// Per-chunk sums of deg -> bsum[NB]
__global__ __launch_bounds__(CHUNK) void chunk_sum_kernel(
    const int* __restrict__ deg, int* __restrict__ bsum) {
  __shared__ int sm[CHUNK];
  int i = blockIdx.x * CHUNK + threadIdx.x;
  sm[threadIdx.x] = (i < NN) ? deg[i] : 0;
  __syncthreads();
  for (int off = CHUNK / 2; off > 0; off >>= 1) {
    if (threadIdx.x < off) sm[threadIdx.x] += sm[threadIdx.x + off];
    __syncthreads();
  }
  if (threadIdx.x == 0) bsum[blockIdx.x] = sm[0];
}

// Exclusive scan of bsum (tiny: NB=49) -> boff[NB]
__global__ __launch_bounds__(64) void scan_bsum_kernel(
    const int* __restrict__ bsum, int* __restrict__ boff) {
  if (threadIdx.x == 0) {
    int run = 0;
    for (int b = 0; b < NB; ++b) {
      boff[b] = run;
      run += bsum[b];
    }
  }
}

// Per-chunk exclusive scan + chunk offset -> row_ptr, cursor
__global__ __launch_bounds__(CHUNK) void emit_rowptr_kernel(
    const int* __restrict__ deg, const int* __restrict__ boff,
    int* __restrict__ row_ptr, int* __restrict__ cursor) {
  __shared__ int sm[CHUNK];
  int i = blockIdx.x * CHUNK + threadIdx.x;
  int v = (i < NN) ? deg[i] : 0;
  sm[threadIdx.x] = v;
  __syncthreads();
  // Hillis-Steele inclusive scan
  for (int off = 1; off < CHUNK; off <<= 1) {
    int t = (threadIdx.x >= off) ? sm[threadIdx.x - off] : 0;
    __syncthreads();
    sm[threadIdx.x] += t;
    __syncthreads();
  }
  int excl = sm[threadIdx.x] - v;
  if (i < NN) {
    int val = boff[blockIdx.x] + excl;
    row_ptr[i] = val;
    cursor[i] = val;
  }
  if (blockIdx.x == 0 && threadIdx.x == 0) row_ptr[NN] = NE;
}

// col[pos] = src for each edge, pos allocated via cursor atomics.
__global__ __launch_bounds__(256) void place_kernel(const int* __restrict__ ei,
                                                    int* __restrict__ cursor,
                                                    int* __restrict__ col) {
  int e = blockIdx.x * 256 + threadIdx.x;
  if (e >= NE) return;
  int src = ei[e];
  int dst = ei[NE + e];
  int pos = atomicAdd(&cursor[dst], 1);
  col[pos] = src;
}

// ---------------- aggregation (gather, no atomics) ----------------
// 16 threads per node, float4 per thread. col[j] broadcast-loaded by the 16
// threads (L1); feat rows are 256B coalesced segments (LLC-resident, 12.8MB).
__global__ __launch_bounds__(256) void gather_csr(
    const float* __restrict__ feat, const int* __restrict__ row_ptr,
    const int* __restrict__ col, float* __restrict__ agg) {
  int gid = blockIdx.x * 256 + threadIdx.x;
  int v = gid >> 4;
  int q = gid & 15;
  if (v >= NN) return;
  int beg = row_ptr[v], end = row_ptr[v + 1];
  float4 acc = {0.f, 0.f, 0.f, 0.f};
  for (int j = beg; j < end; ++j) {
    int s = col[j];
    float4 f = *reinterpret_cast<const float4*>(feat + (size_t)s * 64 + q * 4);
    acc.x += f.x;
    acc.y += f.y;
    acc.z += f.z;
    acc.w += f.w;
  }
  *reinterpret_cast<float4*>(agg + (size_t)v * 64 + q * 4) = acc;
}

// ---------------- fused GEMM ----------------
// out[row,:] = relu(A[row,:] @ Wl + Hr[row,:] @ Wr + b)
// Block = 256 threads = 64 rows x 4 col-chunks of 16. Weights in LDS (32 KB).
// NOTE: called with out==A for layer 2 (in-place). Safe: each row's 4
// producer threads are in one wave; all row loads precede the stores in
// program order and the stores' waitcnt drains the whole wave's loads.
// A/out deliberately NOT __restrict__.
__global__ __launch_bounds__(256) void sage_lin_relu(
    const float* A, const float* Hr, const float* __restrict__ Wl,
    const float* __restrict__ Wr, const float* __restrict__ bias, float* out) {
  __shared__ float sWl[64 * 64];
  __shared__ float sWr[64 * 64];
  int tid = threadIdx.x;
#pragma unroll
  for (int i = 0; i < 4; ++i) {
    int idx = i * 1024 + tid * 4;
    *reinterpret_cast<float4*>(sWl + idx) =
        *reinterpret_cast<const float4*>(Wl + idx);
    *reinterpret_cast<float4*>(sWr + idx) =
        *reinterpret_cast<const float4*>(Wr + idx);
  }
  __syncthreads();
  int r = tid >> 2, c = tid & 3;
  long row = (long)blockIdx.x * 64 + r;
  if (row >= NN) return;
  const float4* A4 = reinterpret_cast<const float4*>(A + row * 64);
  const float4* H4 = reinterpret_cast<const float4*>(Hr + row * 64);
  float acc[16];
#pragma unroll
  for (int j = 0; j < 16; ++j) acc[j] = bias[c * 16 + j];
#pragma unroll 4
  for (int k4 = 0; k4 < 16; ++k4) {
    float4 a4 = A4[k4];
    float4 h4 = H4[k4];
    float av[4] = {a4.x, a4.y, a4.z, a4.w};
    float hv[4] = {h4.x, h4.y, h4.z, h4.w};
    const float* wl = sWl + k4 * 4 * 64 + c * 16;
    const float* wr = sWr + k4 * 4 * 64 + c * 16;
#pragma unroll
    for (int kk = 0; kk < 4; ++kk) {
#pragma unroll
      for (int j = 0; j < 16; ++j) {
        acc[j] += av[kk] * wl[kk * 64 + j] + hv[kk] * wr[kk * 64 + j];
      }
    }
  }
  float* o = out + row * 64 + c * 16;
#pragma unroll
  for (int j = 0; j < 16; ++j) o[j] = fmaxf(acc[j], 0.0f);
}

// ---------------- pooling (sorted-segment reduction) + head ----------------

// gstart[g] = first node index with batch[i] >= g (batch is sorted).
__global__ __launch_bounds__(64) void graph_start_kernel(
    const int* __restrict__ batch, int* __restrict__ gstart) {
  int g = blockIdx.x * 64 + threadIdx.x;
  if (g > NG) return;
  int lo = 0, hi = NN;
  while (lo < hi) {
    int mid = (lo + hi) >> 1;
    if (batch[mid] < g)
      lo = mid + 1;
    else
      hi = mid;
  }
  gstart[g] = lo;
}

// One 64-thread block per graph: thread c sums column c over the graph's
// contiguous row segment (coalesced 256B per row), then threads 0..15
// apply the head: out[g,o] = bo[o] + sum_k pooled[k] * Wo[k,o].
__global__ __launch_bounds__(64) void pool_head_kernel(
    const float* __restrict__ h2, const int* __restrict__ gstart,
    const float* __restrict__ Wo, const float* __restrict__ bo,
    float* __restrict__ out) {
  __shared__ float sm[64];
  int g = blockIdx.x;
  int c = threadIdx.x;
  int beg = gstart[g], end = gstart[g + 1];
  float acc = 0.f;
  for (int i = beg; i < end; ++i) acc += h2[(size_t)i * 64 + c];
  sm[c] = acc;
  __syncthreads();
  if (c < NO) {
    float o = bo[c];
#pragma unroll
    for (int k = 0; k < 64; ++k) o += sm[k] * Wo[k * 16 + c];
    out[g * 16 + c] = o;
  }
}

extern "C" void kernel_launch(void* const* d_in, const int* in_sizes, int n_in,
                              void* d_out, int out_size, void* d_ws,
                              size_t ws_size, hipStream_t stream) {
  const float* x = (const float*)d_in[0];
  const int* ei = (const int*)d_in[1];
  const int* batch = (const int*)d_in[2];
  const float* Wl1 = (const float*)d_in[3];
  const float* Wr1 = (const float*)d_in[4];
  const float* b1 = (const float*)d_in[5];
  const float* Wl2 = (const float*)d_in[6];
  const float* Wr2 = (const float*)d_in[7];
  const float* b2 = (const float*)d_in[8];
  const float* Wo = (const float*)d_in[9];
  const float* bo = (const float*)d_in[10];
  float* out = (float*)d_out;

  // Workspace layout: ints first, then floats.
  int* deg = (int*)d_ws;              // NN
  int* row_ptr = deg + NN;            // NN+1
  int* cursor = row_ptr + NN + 1;     // NN
  int* bsum = cursor + NN;            // NB
  int* boff = bsum + NB;              // NB
  int* gstart = boff + NB;            // NG+1
  int* col = gstart + NG + 1;         // NE
  float* agg = (float*)(col + NE);    // NN*64
  float* h1 = agg + (size_t)NN * 64;  // NN*64

  hipMemsetAsync(deg, 0, (size_t)NN * sizeof(int), stream);

  const int eblocks = (NE + 255) / 256;
  const int gather_blocks = (NN * 16 + 255) / 256;
  const int gemm_blocks = (NN + 63) / 64;

  // CSR build (once; reused by both layers) + graph segment bounds
  hist_kernel<<<eblocks, 256, 0, stream>>>(ei, deg);
  chunk_sum_kernel<<<NB, CHUNK, 0, stream>>>(deg, bsum);
  scan_bsum_kernel<<<1, 64, 0, stream>>>(bsum, boff);
  emit_rowptr_kernel<<<NB, CHUNK, 0, stream>>>(deg, boff, row_ptr, cursor);
  place_kernel<<<eblocks, 256, 0, stream>>>(ei, cursor, col);
  graph_start_kernel<<<(NG + 64) / 64, 64, 0, stream>>>(batch, gstart);

  // Layer 1
  gather_csr<<<gather_blocks, 256, 0, stream>>>(x, row_ptr, col, agg);
  sage_lin_relu<<<gemm_blocks, 256, 0, stream>>>(agg, x, Wl1, Wr1, b1, h1);

  // Layer 2: gather h1 -> agg... wait, agg holds layer-1 aggregate; safe to
  // overwrite now. GEMM then writes h2 in-place into agg.
  gather_csr<<<gather_blocks, 256, 0, stream>>>(h1, row_ptr, col, agg);
  sage_lin_relu<<<gemm_blocks, 256, 0, stream>>>(agg, h1, Wl2, Wr2, b2, agg);

  // Pool (segmented, no atomics) + head
  pool_head_kernel<<<NG, 64, 0, stream>>>(agg, gstart, Wo, bo, out);
}

// Round 4
// 367.320 us; speedup vs baseline: 5.7476x; 1.0743x over previous
//
#include <hip/hip_runtime.h>

// GNN: 2x SAGEConv(sum) + global_add_pool + Linear head.
// N=50000 nodes, E=1e6 edges, D=H=64, G=512 graphs, O=16.
//
// R1: CSR gather replaced scatter atomics (2111 -> 606 us).
// R2: sorted-segment pooling replaced atomic pooling (606 -> 395 us).
// R3: place_kernel (80 us; 68 MB HBM writes for a 4 MB col array - random
// 4B stores each cost a ~68B line writeback) replaced by binned counting
// sort: LDS-binned bucket scatter (98 buckets of 512 nodes, packed 4B
// edges, ~80B contiguous chunks) + bucket-local placement (cursor atomics
// in 2KB window, col writes in 40KB window -> L2 line merging).

namespace {
constexpr int NN = 50000;
constexpr int NE = 1000000;
constexpr int NG = 512;
constexpr int NO = 16;
constexpr int CHUNK = 1024;
constexpr int NB = (NN + CHUNK - 1) / CHUNK;  // 49 scan blocks
constexpr int KB = 98;                        // buckets: dst>>9 (512 nodes)
constexpr int EPT = 8;                        // edges per thread (pass 1)
constexpr int EPB = 256 * EPT;                // 2048 edges per block
constexpr int SBLK = (NE + EPB - 1) / EPB;    // 489 blocks
}

// ---------------- CSR build ----------------

__global__ __launch_bounds__(256) void hist_kernel(const int* __restrict__ ei,
                                                   int* __restrict__ deg) {
  int e = blockIdx.x * 256 + threadIdx.x;
  if (e < NE) atomicAdd(&deg[ei[NE + e]], 1);
}

// Per-chunk sums of deg -> bsum[NB]
__global__ __launch_bounds__(CHUNK) void chunk_sum_kernel(
    const int* __restrict__ deg, int* __restrict__ bsum) {
  __shared__ int sm[CHUNK];
  int i = blockIdx.x * CHUNK + threadIdx.x;
  sm[threadIdx.x] = (i < NN) ? deg[i] : 0;
  __syncthreads();
  for (int off = CHUNK / 2; off > 0; off >>= 1) {
    if (threadIdx.x < off) sm[threadIdx.x] += sm[threadIdx.x + off];
    __syncthreads();
  }
  if (threadIdx.x == 0) bsum[blockIdx.x] = sm[0];
}

// Exclusive scan of bsum (tiny: NB=49) -> boff[NB]
__global__ __launch_bounds__(64) void scan_bsum_kernel(
    const int* __restrict__ bsum, int* __restrict__ boff) {
  if (threadIdx.x == 0) {
    int run = 0;
    for (int b = 0; b < NB; ++b) {
      boff[b] = run;
      run += bsum[b];
    }
  }
}

// Per-chunk exclusive scan + chunk offset -> row_ptr, cursor
__global__ __launch_bounds__(CHUNK) void emit_rowptr_kernel(
    const int* __restrict__ deg, const int* __restrict__ boff,
    int* __restrict__ row_ptr, int* __restrict__ cursor) {
  __shared__ int sm[CHUNK];
  int i = blockIdx.x * CHUNK + threadIdx.x;
  int v = (i < NN) ? deg[i] : 0;
  sm[threadIdx.x] = v;
  __syncthreads();
  for (int off = 1; off < CHUNK; off <<= 1) {
    int t = (threadIdx.x >= off) ? sm[threadIdx.x - off] : 0;
    __syncthreads();
    sm[threadIdx.x] += t;
    __syncthreads();
  }
  int excl = sm[threadIdx.x] - v;
  if (i < NN) {
    int val = boff[blockIdx.x] + excl;
    row_ptr[i] = val;
    cursor[i] = val;
  }
  if (blockIdx.x == 0 && threadIdx.x == 0) row_ptr[NN] = NE;
}

// bucket cursors start at each bucket's col base (free from row_ptr).
__global__ __launch_bounds__(128) void binit_kernel(
    const int* __restrict__ row_ptr, int* __restrict__ bcursor) {
  int b = threadIdx.x;
  if (b < KB) bcursor[b] = row_ptr[b << 9];
}

// Pass 1: LDS-binned scatter of packed edges into bucket-contiguous ebuf.
__global__ __launch_bounds__(256) void bucket_scatter(
    const int* __restrict__ ei, int* __restrict__ bcursor,
    unsigned int* __restrict__ ebuf) {
  __shared__ int cnt[KB];
  __shared__ int base[KB];
  int t = threadIdx.x;
  if (t < KB) cnt[t] = 0;
  __syncthreads();
  int e0 = blockIdx.x * EPB;
  unsigned int pk[EPT];
#pragma unroll
  for (int i = 0; i < EPT; ++i) {
    int e = e0 + i * 256 + t;
    if (e < NE) {
      unsigned int src = (unsigned int)ei[e];
      unsigned int dst = (unsigned int)ei[NE + e];
      pk[i] = (dst << 16) | src;
      atomicAdd(&cnt[dst >> 9], 1);
    } else {
      pk[i] = 0xFFFFFFFFu;
    }
  }
  __syncthreads();
  if (t < KB) {
    base[t] = atomicAdd(&bcursor[t], cnt[t]);
    cnt[t] = 0;
  }
  __syncthreads();
#pragma unroll
  for (int i = 0; i < EPT; ++i) {
    if (pk[i] != 0xFFFFFFFFu) {
      int b = pk[i] >> 25;  // dst >> 9
      int r = atomicAdd(&cnt[b], 1);
      ebuf[base[b] + r] = pk[i];
    }
  }
}

// Pass 2: bucket-local exact placement (cursor + col windows are L2-local).
__global__ __launch_bounds__(256) void local_place(
    const unsigned int* __restrict__ ebuf, int* __restrict__ cursor,
    int* __restrict__ col) {
  int e = blockIdx.x * 256 + threadIdx.x;
  if (e >= NE) return;
  unsigned int p = ebuf[e];
  int pos = atomicAdd(&cursor[p >> 16], 1);
  col[pos] = (int)(p & 0xFFFFu);
}

// ---------------- aggregation (gather, no atomics) ----------------
__global__ __launch_bounds__(256) void gather_csr(
    const float* __restrict__ feat, const int* __restrict__ row_ptr,
    const int* __restrict__ col, float* __restrict__ agg) {
  int gid = blockIdx.x * 256 + threadIdx.x;
  int v = gid >> 4;
  int q = gid & 15;
  if (v >= NN) return;
  int beg = row_ptr[v], end = row_ptr[v + 1];
  float4 acc = {0.f, 0.f, 0.f, 0.f};
  for (int j = beg; j < end; ++j) {
    int s = col[j];
    float4 f = *reinterpret_cast<const float4*>(feat + (size_t)s * 64 + q * 4);
    acc.x += f.x;
    acc.y += f.y;
    acc.z += f.z;
    acc.w += f.w;
  }
  *reinterpret_cast<float4*>(agg + (size_t)v * 64 + q * 4) = acc;
}

// ---------------- fused GEMM ----------------
// out[row,:] = relu(A[row,:] @ Wl + Hr[row,:] @ Wr + b)
// Called with out==A for layer 2 (in-place; safe, see R2 note).
__global__ __launch_bounds__(256) void sage_lin_relu(
    const float* A, const float* Hr, const float* __restrict__ Wl,
    const float* __restrict__ Wr, const float* __restrict__ bias, float* out) {
  __shared__ float sWl[64 * 64];
  __shared__ float sWr[64 * 64];
  int tid = threadIdx.x;
#pragma unroll
  for (int i = 0; i < 4; ++i) {
    int idx = i * 1024 + tid * 4;
    *reinterpret_cast<float4*>(sWl + idx) =
        *reinterpret_cast<const float4*>(Wl + idx);
    *reinterpret_cast<float4*>(sWr + idx) =
        *reinterpret_cast<const float4*>(Wr + idx);
  }
  __syncthreads();
  int r = tid >> 2, c = tid & 3;
  long row = (long)blockIdx.x * 64 + r;
  if (row >= NN) return;
  const float4* A4 = reinterpret_cast<const float4*>(A + row * 64);
  const float4* H4 = reinterpret_cast<const float4*>(Hr + row * 64);
  float acc[16];
#pragma unroll
  for (int j = 0; j < 16; ++j) acc[j] = bias[c * 16 + j];
#pragma unroll 4
  for (int k4 = 0; k4 < 16; ++k4) {
    float4 a4 = A4[k4];
    float4 h4 = H4[k4];
    float av[4] = {a4.x, a4.y, a4.z, a4.w};
    float hv[4] = {h4.x, h4.y, h4.z, h4.w};
    const float* wl = sWl + k4 * 4 * 64 + c * 16;
    const float* wr = sWr + k4 * 4 * 64 + c * 16;
#pragma unroll
    for (int kk = 0; kk < 4; ++kk) {
#pragma unroll
      for (int j = 0; j < 16; ++j) {
        acc[j] += av[kk] * wl[kk * 64 + j] + hv[kk] * wr[kk * 64 + j];
      }
    }
  }
  float* o = out + row * 64 + c * 16;
#pragma unroll
  for (int j = 0; j < 16; ++j) o[j] = fmaxf(acc[j], 0.0f);
}

// ---------------- pooling (sorted-segment reduction) + head ----------------

__global__ __launch_bounds__(64) void graph_start_kernel(
    const int* __restrict__ batch, int* __restrict__ gstart) {
  int g = blockIdx.x * 64 + threadIdx.x;
  if (g > NG) return;
  int lo = 0, hi = NN;
  while (lo < hi) {
    int mid = (lo + hi) >> 1;
    if (batch[mid] < g)
      lo = mid + 1;
    else
      hi = mid;
  }
  gstart[g] = lo;
}

__global__ __launch_bounds__(64) void pool_head_kernel(
    const float* __restrict__ h2, const int* __restrict__ gstart,
    const float* __restrict__ Wo, const float* __restrict__ bo,
    float* __restrict__ out) {
  __shared__ float sm[64];
  int g = blockIdx.x;
  int c = threadIdx.x;
  int beg = gstart[g], end = gstart[g + 1];
  float acc = 0.f;
  for (int i = beg; i < end; ++i) acc += h2[(size_t)i * 64 + c];
  sm[c] = acc;
  __syncthreads();
  if (c < NO) {
    float o = bo[c];
#pragma unroll
    for (int k = 0; k < 64; ++k) o += sm[k] * Wo[k * 16 + c];
    out[g * 16 + c] = o;
  }
}

extern "C" void kernel_launch(void* const* d_in, const int* in_sizes, int n_in,
                              void* d_out, int out_size, void* d_ws,
                              size_t ws_size, hipStream_t stream) {
  const float* x = (const float*)d_in[0];
  const int* ei = (const int*)d_in[1];
  const int* batch = (const int*)d_in[2];
  const float* Wl1 = (const float*)d_in[3];
  const float* Wr1 = (const float*)d_in[4];
  const float* b1 = (const float*)d_in[5];
  const float* Wl2 = (const float*)d_in[6];
  const float* Wr2 = (const float*)d_in[7];
  const float* b2 = (const float*)d_in[8];
  const float* Wo = (const float*)d_in[9];
  const float* bo = (const float*)d_in[10];
  float* out = (float*)d_out;

  // Workspace layout: ints first, then floats.
  int* deg = (int*)d_ws;              // NN
  int* row_ptr = deg + NN;            // NN+1
  int* cursor = row_ptr + NN + 1;     // NN
  int* bsum = cursor + NN;            // NB
  int* boff = bsum + NB;              // NB
  int* gstart = boff + NB;            // NG+1
  int* bcursor = gstart + NG + 1;     // KB
  int* col = bcursor + KB;            // NE
  float* agg = (float*)(col + NE);    // NN*64
  float* h1 = agg + (size_t)NN * 64;  // NN*64
  // ebuf (NE uint32 = 4MB) aliases agg: only live during CSR build,
  // before the first gather_csr writes agg.
  unsigned int* ebuf = (unsigned int*)agg;

  hipMemsetAsync(deg, 0, (size_t)NN * sizeof(int), stream);

  const int eblocks = (NE + 255) / 256;
  const int gather_blocks = (NN * 16 + 255) / 256;
  const int gemm_blocks = (NN + 63) / 64;

  // CSR build (once; reused by both layers) + graph segment bounds
  hist_kernel<<<eblocks, 256, 0, stream>>>(ei, deg);
  chunk_sum_kernel<<<NB, CHUNK, 0, stream>>>(deg, bsum);
  scan_bsum_kernel<<<1, 64, 0, stream>>>(bsum, boff);
  emit_rowptr_kernel<<<NB, CHUNK, 0, stream>>>(deg, boff, row_ptr, cursor);
  binit_kernel<<<1, 128, 0, stream>>>(row_ptr, bcursor);
  bucket_scatter<<<SBLK, 256, 0, stream>>>(ei, bcursor, ebuf);
  local_place<<<eblocks, 256, 0, stream>>>(ebuf, cursor, col);
  graph_start_kernel<<<(NG + 64) / 64, 64, 0, stream>>>(batch, gstart);

  // Layer 1
  gather_csr<<<gather_blocks, 256, 0, stream>>>(x, row_ptr, col, agg);
  sage_lin_relu<<<gemm_blocks, 256, 0, stream>>>(agg, x, Wl1, Wr1, b1, h1);

  // Layer 2 (h2 written in-place into agg)
  gather_csr<<<gather_blocks, 256, 0, stream>>>(h1, row_ptr, col, agg);
  sage_lin_relu<<<gemm_blocks, 256, 0, stream>>>(agg, h1, Wl2, Wr2, b2, agg);

  // Pool (segmented, no atomics) + head
  pool_head_kernel<<<NG, 64, 0, stream>>>(agg, gstart, Wo, bo, out);
}

// Round 5
// 324.527 us; speedup vs baseline: 6.5055x; 1.1319x over previous
//
#include <hip/hip_runtime.h>

// GNN: 2x SAGEConv(sum) + global_add_pool + Linear head.
// N=50000 nodes, E=1e6 edges, D=H=64, G=512 graphs, O=16.
//
// R1: CSR gather replaced scatter atomics (2111 -> 606 us).
// R2: sorted-segment pooling replaced atomic pooling (606 -> 395 us).
// R3: binned counting sort for CSR build (395 -> 367 us).
// R4: gather FETCH_SIZE=132MB for a 12.8MB feature matrix (each random src
// row refetched into all 8 XCD L2s; LLC-fill bound). Halve bytes: bf16
// feature storage end-to-end (fp32 accumulate everywhere). Gather: 8
// threads/node, 16B uint4 loads = 1x128B line per edge instead of 2.

namespace {
constexpr int NN = 50000;
constexpr int NE = 1000000;
constexpr int NG = 512;
constexpr int NO = 16;
constexpr int CHUNK = 1024;
constexpr int NB = (NN + CHUNK - 1) / CHUNK;  // 49 scan blocks
constexpr int KB = 98;                        // buckets: dst>>9 (512 nodes)
constexpr int EPT = 8;                        // edges per thread (pass 1)
constexpr int EPB = 256 * EPT;                // 2048 edges per block
constexpr int SBLK = (NE + EPB - 1) / EPB;    // 489 blocks
}

__device__ __forceinline__ unsigned short f2bf(float f) {
  unsigned u = __float_as_uint(f);
  u += 0x7FFFu + ((u >> 16) & 1u);  // round-to-nearest-even
  return (unsigned short)(u >> 16);
}
__device__ __forceinline__ float bf2f(unsigned short s) {
  return __uint_as_float(((unsigned)s) << 16);
}

// ---------------- CSR build ----------------

__global__ __launch_bounds__(256) void hist_kernel(const int* __restrict__ ei,
                                                   int* __restrict__ deg) {
  int e = blockIdx.x * 256 + threadIdx.x;
  if (e < NE) atomicAdd(&deg[ei[NE + e]], 1);
}

__global__ __launch_bounds__(CHUNK) void chunk_sum_kernel(
    const int* __restrict__ deg, int* __restrict__ bsum) {
  __shared__ int sm[CHUNK];
  int i = blockIdx.x * CHUNK + threadIdx.x;
  sm[threadIdx.x] = (i < NN) ? deg[i] : 0;
  __syncthreads();
  for (int off = CHUNK / 2; off > 0; off >>= 1) {
    if (threadIdx.x < off) sm[threadIdx.x] += sm[threadIdx.x + off];
    __syncthreads();
  }
  if (threadIdx.x == 0) bsum[blockIdx.x] = sm[0];
}

__global__ __launch_bounds__(64) void scan_bsum_kernel(
    const int* __restrict__ bsum, int* __restrict__ boff) {
  if (threadIdx.x == 0) {
    int run = 0;
    for (int b = 0; b < NB; ++b) {
      boff[b] = run;
      run += bsum[b];
    }
  }
}

__global__ __launch_bounds__(CHUNK) void emit_rowptr_kernel(
    const int* __restrict__ deg, const int* __restrict__ boff,
    int* __restrict__ row_ptr, int* __restrict__ cursor) {
  __shared__ int sm[CHUNK];
  int i = blockIdx.x * CHUNK + threadIdx.x;
  int v = (i < NN) ? deg[i] : 0;
  sm[threadIdx.x] = v;
  __syncthreads();
  for (int off = 1; off < CHUNK; off <<= 1) {
    int t = (threadIdx.x >= off) ? sm[threadIdx.x - off] : 0;
    __syncthreads();
    sm[threadIdx.x] += t;
    __syncthreads();
  }
  int excl = sm[threadIdx.x] - v;
  if (i < NN) {
    int val = boff[blockIdx.x] + excl;
    row_ptr[i] = val;
    cursor[i] = val;
  }
  if (blockIdx.x == 0 && threadIdx.x == 0) row_ptr[NN] = NE;
}

__global__ __launch_bounds__(128) void binit_kernel(
    const int* __restrict__ row_ptr, int* __restrict__ bcursor) {
  int b = threadIdx.x;
  if (b < KB) bcursor[b] = row_ptr[b << 9];
}

// Pass 1: LDS-binned scatter of packed edges into bucket-contiguous ebuf.
__global__ __launch_bounds__(256) void bucket_scatter(
    const int* __restrict__ ei, int* __restrict__ bcursor,
    unsigned int* __restrict__ ebuf) {
  __shared__ int cnt[KB];
  __shared__ int base[KB];
  int t = threadIdx.x;
  if (t < KB) cnt[t] = 0;
  __syncthreads();
  int e0 = blockIdx.x * EPB;
  unsigned int pk[EPT];
#pragma unroll
  for (int i = 0; i < EPT; ++i) {
    int e = e0 + i * 256 + t;
    if (e < NE) {
      unsigned int src = (unsigned int)ei[e];
      unsigned int dst = (unsigned int)ei[NE + e];
      pk[i] = (dst << 16) | src;
      atomicAdd(&cnt[dst >> 9], 1);
    } else {
      pk[i] = 0xFFFFFFFFu;
    }
  }
  __syncthreads();
  if (t < KB) {
    base[t] = atomicAdd(&bcursor[t], cnt[t]);
    cnt[t] = 0;
  }
  __syncthreads();
#pragma unroll
  for (int i = 0; i < EPT; ++i) {
    if (pk[i] != 0xFFFFFFFFu) {
      int b = pk[i] >> 25;  // dst >> 9
      int r = atomicAdd(&cnt[b], 1);
      ebuf[base[b] + r] = pk[i];
    }
  }
}

// Pass 2: bucket-local exact placement (cursor + col windows are L2-local).
__global__ __launch_bounds__(256) void local_place(
    const unsigned int* __restrict__ ebuf, int* __restrict__ cursor,
    int* __restrict__ col) {
  int e = blockIdx.x * 256 + threadIdx.x;
  if (e >= NE) return;
  unsigned int p = ebuf[e];
  int pos = atomicAdd(&cursor[p >> 16], 1);
  col[pos] = (int)(p & 0xFFFFu);
}

// ---------------- bf16 conversion ----------------
__global__ __launch_bounds__(256) void cvt_f32_bf16(
    const float* __restrict__ in, unsigned short* __restrict__ out, int n8) {
  int i = blockIdx.x * 256 + threadIdx.x;
  if (i >= n8) return;
  const float4* p = reinterpret_cast<const float4*>(in + (size_t)i * 8);
  float4 a = p[0], b = p[1];
  uint4 u;
  u.x = (unsigned)f2bf(a.x) | ((unsigned)f2bf(a.y) << 16);
  u.y = (unsigned)f2bf(a.z) | ((unsigned)f2bf(a.w) << 16);
  u.z = (unsigned)f2bf(b.x) | ((unsigned)f2bf(b.y) << 16);
  u.w = (unsigned)f2bf(b.z) | ((unsigned)f2bf(b.w) << 16);
  reinterpret_cast<uint4*>(out)[i] = u;
}

// ---------------- aggregation (gather, bf16, no atomics) ----------------
// 8 threads per node, one 16B uint4 (8 bf16) per thread per neighbor:
// each edge touches exactly one 128B line. fp32 accumulate, bf16 store.
__global__ __launch_bounds__(256) void gather_csr_bf(
    const unsigned short* __restrict__ feat, const int* __restrict__ row_ptr,
    const int* __restrict__ col, unsigned short* __restrict__ agg) {
  int gid = blockIdx.x * 256 + threadIdx.x;
  int v = gid >> 3;
  int q = gid & 7;
  if (v >= NN) return;
  int beg = row_ptr[v], end = row_ptr[v + 1];
  float acc[8] = {0.f, 0.f, 0.f, 0.f, 0.f, 0.f, 0.f, 0.f};
  const uint4* fb = reinterpret_cast<const uint4*>(feat);
  for (int j = beg; j < end; ++j) {
    int s = col[j];
    uint4 u = fb[(size_t)s * 8 + q];
    acc[0] += __uint_as_float(u.x << 16);
    acc[1] += __uint_as_float(u.x & 0xFFFF0000u);
    acc[2] += __uint_as_float(u.y << 16);
    acc[3] += __uint_as_float(u.y & 0xFFFF0000u);
    acc[4] += __uint_as_float(u.z << 16);
    acc[5] += __uint_as_float(u.z & 0xFFFF0000u);
    acc[6] += __uint_as_float(u.w << 16);
    acc[7] += __uint_as_float(u.w & 0xFFFF0000u);
  }
  uint4 o;
  o.x = (unsigned)f2bf(acc[0]) | ((unsigned)f2bf(acc[1]) << 16);
  o.y = (unsigned)f2bf(acc[2]) | ((unsigned)f2bf(acc[3]) << 16);
  o.z = (unsigned)f2bf(acc[4]) | ((unsigned)f2bf(acc[5]) << 16);
  o.w = (unsigned)f2bf(acc[6]) | ((unsigned)f2bf(acc[7]) << 16);
  reinterpret_cast<uint4*>(agg)[(size_t)v * 8 + q] = o;
}

// ---------------- fused GEMM (bf16 in/out, fp32 math) ----------------
// out[row,:] = relu(A[row,:] @ Wl + Hr[row,:] @ Wr + b)
// Block = 256 threads = 64 rows x 4 col-chunks of 16. Weights fp32 in LDS.
// Called with out==A for layer 2 (in-place): each row is read/written only
// by its own 4 same-wave threads; loads precede stores in program order.
// A/out deliberately NOT __restrict__.
__global__ __launch_bounds__(256) void sage_lin_relu_bf(
    const unsigned short* A, const unsigned short* Hr,
    const float* __restrict__ Wl, const float* __restrict__ Wr,
    const float* __restrict__ bias, unsigned short* out) {
  __shared__ float sWl[64 * 64];
  __shared__ float sWr[64 * 64];
  int tid = threadIdx.x;
#pragma unroll
  for (int i = 0; i < 4; ++i) {
    int idx = i * 1024 + tid * 4;
    *reinterpret_cast<float4*>(sWl + idx) =
        *reinterpret_cast<const float4*>(Wl + idx);
    *reinterpret_cast<float4*>(sWr + idx) =
        *reinterpret_cast<const float4*>(Wr + idx);
  }
  __syncthreads();
  int r = tid >> 2, c = tid & 3;
  long row = (long)blockIdx.x * 64 + r;
  if (row >= NN) return;
  const uint4* A4 = reinterpret_cast<const uint4*>(A + row * 64);
  const uint4* H4 = reinterpret_cast<const uint4*>(Hr + row * 64);
  float acc[16];
#pragma unroll
  for (int j = 0; j < 16; ++j) acc[j] = bias[c * 16 + j];
#pragma unroll
  for (int k8 = 0; k8 < 8; ++k8) {
    uint4 ua = A4[k8];
    uint4 uh = H4[k8];
    float av[8], hv[8];
    av[0] = __uint_as_float(ua.x << 16);
    av[1] = __uint_as_float(ua.x & 0xFFFF0000u);
    av[2] = __uint_as_float(ua.y << 16);
    av[3] = __uint_as_float(ua.y & 0xFFFF0000u);
    av[4] = __uint_as_float(ua.z << 16);
    av[5] = __uint_as_float(ua.z & 0xFFFF0000u);
    av[6] = __uint_as_float(ua.w << 16);
    av[7] = __uint_as_float(ua.w & 0xFFFF0000u);
    hv[0] = __uint_as_float(uh.x << 16);
    hv[1] = __uint_as_float(uh.x & 0xFFFF0000u);
    hv[2] = __uint_as_float(uh.y << 16);
    hv[3] = __uint_as_float(uh.y & 0xFFFF0000u);
    hv[4] = __uint_as_float(uh.z << 16);
    hv[5] = __uint_as_float(uh.z & 0xFFFF0000u);
    hv[6] = __uint_as_float(uh.w << 16);
    hv[7] = __uint_as_float(uh.w & 0xFFFF0000u);
    const float* wl = sWl + k8 * 8 * 64 + c * 16;
    const float* wr = sWr + k8 * 8 * 64 + c * 16;
#pragma unroll
    for (int kk = 0; kk < 8; ++kk) {
#pragma unroll
      for (int j = 0; j < 16; ++j) {
        acc[j] += av[kk] * wl[kk * 64 + j] + hv[kk] * wr[kk * 64 + j];
      }
    }
  }
  uint4 o0, o1;
  float r0 = fmaxf(acc[0], 0.f), r1 = fmaxf(acc[1], 0.f);
  float r2 = fmaxf(acc[2], 0.f), r3 = fmaxf(acc[3], 0.f);
  float r4 = fmaxf(acc[4], 0.f), r5 = fmaxf(acc[5], 0.f);
  float r6 = fmaxf(acc[6], 0.f), r7 = fmaxf(acc[7], 0.f);
  o0.x = (unsigned)f2bf(r0) | ((unsigned)f2bf(r1) << 16);
  o0.y = (unsigned)f2bf(r2) | ((unsigned)f2bf(r3) << 16);
  o0.z = (unsigned)f2bf(r4) | ((unsigned)f2bf(r5) << 16);
  o0.w = (unsigned)f2bf(r6) | ((unsigned)f2bf(r7) << 16);
  float s0 = fmaxf(acc[8], 0.f), s1 = fmaxf(acc[9], 0.f);
  float s2 = fmaxf(acc[10], 0.f), s3 = fmaxf(acc[11], 0.f);
  float s4 = fmaxf(acc[12], 0.f), s5 = fmaxf(acc[13], 0.f);
  float s6 = fmaxf(acc[14], 0.f), s7 = fmaxf(acc[15], 0.f);
  o1.x = (unsigned)f2bf(s0) | ((unsigned)f2bf(s1) << 16);
  o1.y = (unsigned)f2bf(s2) | ((unsigned)f2bf(s3) << 16);
  o1.z = (unsigned)f2bf(s4) | ((unsigned)f2bf(s5) << 16);
  o1.w = (unsigned)f2bf(s6) | ((unsigned)f2bf(s7) << 16);
  uint4* op = reinterpret_cast<uint4*>(out + row * 64 + c * 16);
  op[0] = o0;
  op[1] = o1;
}

// ---------------- pooling (sorted-segment reduction) + head ----------------

__global__ __launch_bounds__(64) void graph_start_kernel(
    const int* __restrict__ batch, int* __restrict__ gstart) {
  int g = blockIdx.x * 64 + threadIdx.x;
  if (g > NG) return;
  int lo = 0, hi = NN;
  while (lo < hi) {
    int mid = (lo + hi) >> 1;
    if (batch[mid] < g)
      lo = mid + 1;
    else
      hi = mid;
  }
  gstart[g] = lo;
}

__global__ __launch_bounds__(64) void pool_head_kernel(
    const unsigned short* __restrict__ h2, const int* __restrict__ gstart,
    const float* __restrict__ Wo, const float* __restrict__ bo,
    float* __restrict__ out) {
  __shared__ float sm[64];
  int g = blockIdx.x;
  int c = threadIdx.x;
  int beg = gstart[g], end = gstart[g + 1];
  float acc = 0.f;
  for (int i = beg; i < end; ++i) acc += bf2f(h2[(size_t)i * 64 + c]);
  sm[c] = acc;
  __syncthreads();
  if (c < NO) {
    float o = bo[c];
#pragma unroll
    for (int k = 0; k < 64; ++k) o += sm[k] * Wo[k * 16 + c];
    out[g * 16 + c] = o;
  }
}

extern "C" void kernel_launch(void* const* d_in, const int* in_sizes, int n_in,
                              void* d_out, int out_size, void* d_ws,
                              size_t ws_size, hipStream_t stream) {
  const float* x = (const float*)d_in[0];
  const int* ei = (const int*)d_in[1];
  const int* batch = (const int*)d_in[2];
  const float* Wl1 = (const float*)d_in[3];
  const float* Wr1 = (const float*)d_in[4];
  const float* b1 = (const float*)d_in[5];
  const float* Wl2 = (const float*)d_in[6];
  const float* Wr2 = (const float*)d_in[7];
  const float* b2 = (const float*)d_in[8];
  const float* Wo = (const float*)d_in[9];
  const float* bo = (const float*)d_in[10];
  float* out = (float*)d_out;

  // Workspace: 16B-aligned big arrays first, then ints.
  unsigned short* x_bf = (unsigned short*)d_ws;       // NN*64 bf16 (6.4 MB)
  unsigned short* agg_bf = x_bf + (size_t)NN * 64;    // NN*64 bf16
  unsigned short* h1_bf = agg_bf + (size_t)NN * 64;   // NN*64 bf16
  int* col = (int*)(h1_bf + (size_t)NN * 64);         // NE
  int* deg = col + NE;                                // NN
  int* row_ptr = deg + NN;                            // NN+1
  int* cursor = row_ptr + NN + 1;                     // NN
  int* bsum = cursor + NN;                            // NB
  int* boff = bsum + NB;                              // NB
  int* gstart = boff + NB;                            // NG+1
  int* bcursor = gstart + NG + 1;                     // KB
  // ebuf (NE uint32 = 4MB) aliases agg_bf (6.4MB): dead before gather
  // first writes agg_bf.
  unsigned int* ebuf = (unsigned int*)agg_bf;

  hipMemsetAsync(deg, 0, (size_t)NN * sizeof(int), stream);

  const int eblocks = (NE + 255) / 256;
  const int gather_blocks = (NN * 8 + 255) / 256;
  const int gemm_blocks = (NN + 63) / 64;

  // x -> bf16 (independent of CSR build)
  cvt_f32_bf16<<<(NN * 64 / 8 + 255) / 256, 256, 0, stream>>>(x, x_bf,
                                                              NN * 64 / 8);

  // CSR build (once; reused by both layers) + graph segment bounds
  hist_kernel<<<eblocks, 256, 0, stream>>>(ei, deg);
  chunk_sum_kernel<<<NB, CHUNK, 0, stream>>>(deg, bsum);
  scan_bsum_kernel<<<1, 64, 0, stream>>>(bsum, boff);
  emit_rowptr_kernel<<<NB, CHUNK, 0, stream>>>(deg, boff, row_ptr, cursor);
  binit_kernel<<<1, 128, 0, stream>>>(row_ptr, bcursor);
  bucket_scatter<<<SBLK, 256, 0, stream>>>(ei, bcursor, ebuf);
  local_place<<<eblocks, 256, 0, stream>>>(ebuf, cursor, col);
  graph_start_kernel<<<(NG + 64) / 64, 64, 0, stream>>>(batch, gstart);

  // Layer 1
  gather_csr_bf<<<gather_blocks, 256, 0, stream>>>(x_bf, row_ptr, col, agg_bf);
  sage_lin_relu_bf<<<gemm_blocks, 256, 0, stream>>>(agg_bf, x_bf, Wl1, Wr1, b1,
                                                    h1_bf);

  // Layer 2 (h2 written in-place into agg_bf)
  gather_csr_bf<<<gather_blocks, 256, 0, stream>>>(h1_bf, row_ptr, col,
                                                   agg_bf);
  sage_lin_relu_bf<<<gemm_blocks, 256, 0, stream>>>(agg_bf, h1_bf, Wl2, Wr2,
                                                    b2, agg_bf);

  // Pool (segmented, no atomics) + head
  pool_head_kernel<<<NG, 64, 0, stream>>>(agg_bf, gstart, Wo, bo, out);
}

// Round 6
// 302.293 us; speedup vs baseline: 6.9840x; 1.0736x over previous
//
#include <hip/hip_runtime.h>

// GNN: 2x SAGEConv(sum) + global_add_pool + Linear head.
// N=50000 nodes, E=1e6 edges, D=H=64, G=512 graphs, O=16.
//
// R1: CSR gather replaced scatter atomics (2111 -> 606 us).
// R2: sorted-segment pooling replaced atomic pooling (606 -> 395 us).
// R3: binned counting sort for CSR build (395 -> 367 us).
// R4: bf16 feature storage end-to-end, fp32 accumulate (367 -> 325 us).
// R5: hist_kernel (46 us: 1M contended global atomics, 31MB RMW traffic)
// and the global deg-scan chain replaced by bucket-local counting:
// per-block LDS bucket histogram (48K global atomics), tiny 98-scan,
// then per-bucket LDS degree count + LDS scan -> row_ptr/cursor.

namespace {
constexpr int NN = 50000;
constexpr int NE = 1000000;
constexpr int NG = 512;
constexpr int NO = 16;
constexpr int KB = 98;                      // buckets: dst>>9 (512 nodes)
constexpr int EPT = 8;                      // edges per thread (pass 1)
constexpr int EPB = 256 * EPT;              // 2048 edges per block
constexpr int SBLK = (NE + EPB - 1) / EPB;  // 489 blocks
}

__device__ __forceinline__ unsigned short f2bf(float f) {
  unsigned u = __float_as_uint(f);
  u += 0x7FFFu + ((u >> 16) & 1u);  // round-to-nearest-even
  return (unsigned short)(u >> 16);
}
__device__ __forceinline__ float bf2f(unsigned short s) {
  return __uint_as_float(((unsigned)s) << 16);
}

// ---------------- CSR build (bucketed counting sort) ----------------

// Bucket totals: per-block LDS histogram, one global atomic per
// (block,bucket) -> 48K atomics total (vs 1M in the old hist_kernel).
__global__ __launch_bounds__(256) void bucket_count(
    const int* __restrict__ ei, int* __restrict__ btot) {
  __shared__ int cnt[KB];
  int t = threadIdx.x;
  if (t < KB) cnt[t] = 0;
  __syncthreads();
  int e0 = blockIdx.x * EPB;
#pragma unroll
  for (int i = 0; i < EPT; ++i) {
    int e = e0 + i * 256 + t;
    if (e < NE) atomicAdd(&cnt[ei[NE + e] >> 9], 1);
  }
  __syncthreads();
  if (t < KB && cnt[t] > 0) atomicAdd(&btot[t], cnt[t]);
}

// Exclusive scan of 98 bucket totals -> bbase[KB+1]; seed scatter cursors.
__global__ __launch_bounds__(64) void scan_btot(const int* __restrict__ btot,
                                                int* __restrict__ bbase,
                                                int* __restrict__ bcursor) {
  if (threadIdx.x == 0) {
    int run = 0;
    for (int b = 0; b < KB; ++b) {
      bbase[b] = run;
      bcursor[b] = run;
      run += btot[b];
    }
    bbase[KB] = run;  // == NE
  }
}

// Pass 1: LDS-binned scatter of packed edges into bucket-contiguous ebuf.
__global__ __launch_bounds__(256) void bucket_scatter(
    const int* __restrict__ ei, int* __restrict__ bcursor,
    unsigned int* __restrict__ ebuf) {
  __shared__ int cnt[KB];
  __shared__ int base[KB];
  int t = threadIdx.x;
  if (t < KB) cnt[t] = 0;
  __syncthreads();
  int e0 = blockIdx.x * EPB;
  unsigned int pk[EPT];
#pragma unroll
  for (int i = 0; i < EPT; ++i) {
    int e = e0 + i * 256 + t;
    if (e < NE) {
      unsigned int src = (unsigned int)ei[e];
      unsigned int dst = (unsigned int)ei[NE + e];
      pk[i] = (dst << 16) | src;
      atomicAdd(&cnt[dst >> 9], 1);
    } else {
      pk[i] = 0xFFFFFFFFu;
    }
  }
  __syncthreads();
  if (t < KB) {
    base[t] = atomicAdd(&bcursor[t], cnt[t]);
    cnt[t] = 0;
  }
  __syncthreads();
#pragma unroll
  for (int i = 0; i < EPT; ++i) {
    if (pk[i] != 0xFFFFFFFFu) {
      int b = pk[i] >> 25;  // dst >> 9
      int r = atomicAdd(&cnt[b], 1);
      ebuf[base[b] + r] = pk[i];
    }
  }
}

// Per-bucket: LDS degree count of the bucket's grouped edges, LDS scan,
// emit row_ptr + cursor. Replaces hist/chunk_sum/scan_bsum/emit_rowptr.
__global__ __launch_bounds__(512) void bucket_rowptr(
    const unsigned int* __restrict__ ebuf, const int* __restrict__ bbase,
    int* __restrict__ row_ptr, int* __restrict__ cursor) {
  __shared__ int cnt[512];
  int b = blockIdx.x;
  int t = threadIdx.x;
  cnt[t] = 0;
  __syncthreads();
  int beg = bbase[b], end = bbase[b + 1];
  for (int j = beg + t; j < end; j += 512) {
    atomicAdd(&cnt[(ebuf[j] >> 16) & 511], 1);
  }
  __syncthreads();
  int v = cnt[t];
  // Hillis-Steele inclusive scan over 512 (read all, sync, write, sync)
  for (int off = 1; off < 512; off <<= 1) {
    int u = (t >= off) ? cnt[t - off] : 0;
    __syncthreads();
    cnt[t] += u;
    __syncthreads();
  }
  int excl = cnt[t] - v;
  int node = (b << 9) + t;
  if (node < NN) {
    int val = beg + excl;
    row_ptr[node] = val;
    cursor[node] = val;
  }
  if (b == 0 && t == 0) row_ptr[NN] = NE;
}

// Pass 2: bucket-local exact placement (cursor + col windows are L2-local).
__global__ __launch_bounds__(256) void local_place(
    const unsigned int* __restrict__ ebuf, int* __restrict__ cursor,
    int* __restrict__ col) {
  int e = blockIdx.x * 256 + threadIdx.x;
  if (e >= NE) return;
  unsigned int p = ebuf[e];
  int pos = atomicAdd(&cursor[p >> 16], 1);
  col[pos] = (int)(p & 0xFFFFu);
}

// ---------------- bf16 conversion ----------------
__global__ __launch_bounds__(256) void cvt_f32_bf16(
    const float* __restrict__ in, unsigned short* __restrict__ out, int n8) {
  int i = blockIdx.x * 256 + threadIdx.x;
  if (i >= n8) return;
  const float4* p = reinterpret_cast<const float4*>(in + (size_t)i * 8);
  float4 a = p[0], b = p[1];
  uint4 u;
  u.x = (unsigned)f2bf(a.x) | ((unsigned)f2bf(a.y) << 16);
  u.y = (unsigned)f2bf(a.z) | ((unsigned)f2bf(a.w) << 16);
  u.z = (unsigned)f2bf(b.x) | ((unsigned)f2bf(b.y) << 16);
  u.w = (unsigned)f2bf(b.z) | ((unsigned)f2bf(b.w) << 16);
  reinterpret_cast<uint4*>(out)[i] = u;
}

// ---------------- aggregation (gather, bf16, no atomics) ----------------
// 8 threads per node, one 16B uint4 (8 bf16) per thread per neighbor:
// each edge touches exactly one 128B line. fp32 accumulate, bf16 store.
__global__ __launch_bounds__(256) void gather_csr_bf(
    const unsigned short* __restrict__ feat, const int* __restrict__ row_ptr,
    const int* __restrict__ col, unsigned short* __restrict__ agg) {
  int gid = blockIdx.x * 256 + threadIdx.x;
  int v = gid >> 3;
  int q = gid & 7;
  if (v >= NN) return;
  int beg = row_ptr[v], end = row_ptr[v + 1];
  float acc[8] = {0.f, 0.f, 0.f, 0.f, 0.f, 0.f, 0.f, 0.f};
  const uint4* fb = reinterpret_cast<const uint4*>(feat);
  for (int j = beg; j < end; ++j) {
    int s = col[j];
    uint4 u = fb[(size_t)s * 8 + q];
    acc[0] += __uint_as_float(u.x << 16);
    acc[1] += __uint_as_float(u.x & 0xFFFF0000u);
    acc[2] += __uint_as_float(u.y << 16);
    acc[3] += __uint_as_float(u.y & 0xFFFF0000u);
    acc[4] += __uint_as_float(u.z << 16);
    acc[5] += __uint_as_float(u.z & 0xFFFF0000u);
    acc[6] += __uint_as_float(u.w << 16);
    acc[7] += __uint_as_float(u.w & 0xFFFF0000u);
  }
  uint4 o;
  o.x = (unsigned)f2bf(acc[0]) | ((unsigned)f2bf(acc[1]) << 16);
  o.y = (unsigned)f2bf(acc[2]) | ((unsigned)f2bf(acc[3]) << 16);
  o.z = (unsigned)f2bf(acc[4]) | ((unsigned)f2bf(acc[5]) << 16);
  o.w = (unsigned)f2bf(acc[6]) | ((unsigned)f2bf(acc[7]) << 16);
  reinterpret_cast<uint4*>(agg)[(size_t)v * 8 + q] = o;
}

// ---------------- fused GEMM (bf16 in/out, fp32 math) ----------------
// out[row,:] = relu(A[row,:] @ Wl + Hr[row,:] @ Wr + b)
// Block = 256 threads = 64 rows x 4 col-chunks of 16. Weights fp32 in LDS.
// Called with out==A for layer 2 (in-place): each row is read/written only
// by its own 4 same-wave threads; loads precede stores in program order.
// A/out deliberately NOT __restrict__.
__global__ __launch_bounds__(256) void sage_lin_relu_bf(
    const unsigned short* A, const unsigned short* Hr,
    const float* __restrict__ Wl, const float* __restrict__ Wr,
    const float* __restrict__ bias, unsigned short* out) {
  __shared__ float sWl[64 * 64];
  __shared__ float sWr[64 * 64];
  int tid = threadIdx.x;
#pragma unroll
  for (int i = 0; i < 4; ++i) {
    int idx = i * 1024 + tid * 4;
    *reinterpret_cast<float4*>(sWl + idx) =
        *reinterpret_cast<const float4*>(Wl + idx);
    *reinterpret_cast<float4*>(sWr + idx) =
        *reinterpret_cast<const float4*>(Wr + idx);
  }
  __syncthreads();
  int r = tid >> 2, c = tid & 3;
  long row = (long)blockIdx.x * 64 + r;
  if (row >= NN) return;
  const uint4* A4 = reinterpret_cast<const uint4*>(A + row * 64);
  const uint4* H4 = reinterpret_cast<const uint4*>(Hr + row * 64);
  float acc[16];
#pragma unroll
  for (int j = 0; j < 16; ++j) acc[j] = bias[c * 16 + j];
#pragma unroll
  for (int k8 = 0; k8 < 8; ++k8) {
    uint4 ua = A4[k8];
    uint4 uh = H4[k8];
    float av[8], hv[8];
    av[0] = __uint_as_float(ua.x << 16);
    av[1] = __uint_as_float(ua.x & 0xFFFF0000u);
    av[2] = __uint_as_float(ua.y << 16);
    av[3] = __uint_as_float(ua.y & 0xFFFF0000u);
    av[4] = __uint_as_float(ua.z << 16);
    av[5] = __uint_as_float(ua.z & 0xFFFF0000u);
    av[6] = __uint_as_float(ua.w << 16);
    av[7] = __uint_as_float(ua.w & 0xFFFF0000u);
    hv[0] = __uint_as_float(uh.x << 16);
    hv[1] = __uint_as_float(uh.x & 0xFFFF0000u);
    hv[2] = __uint_as_float(uh.y << 16);
    hv[3] = __uint_as_float(uh.y & 0xFFFF0000u);
    hv[4] = __uint_as_float(uh.z << 16);
    hv[5] = __uint_as_float(uh.z & 0xFFFF0000u);
    hv[6] = __uint_as_float(uh.w << 16);
    hv[7] = __uint_as_float(uh.w & 0xFFFF0000u);
    const float* wl = sWl + k8 * 8 * 64 + c * 16;
    const float* wr = sWr + k8 * 8 * 64 + c * 16;
#pragma unroll
    for (int kk = 0; kk < 8; ++kk) {
#pragma unroll
      for (int j = 0; j < 16; ++j) {
        acc[j] += av[kk] * wl[kk * 64 + j] + hv[kk] * wr[kk * 64 + j];
      }
    }
  }
  uint4 o0, o1;
  float r0 = fmaxf(acc[0], 0.f), r1 = fmaxf(acc[1], 0.f);
  float r2 = fmaxf(acc[2], 0.f), r3 = fmaxf(acc[3], 0.f);
  float r4 = fmaxf(acc[4], 0.f), r5 = fmaxf(acc[5], 0.f);
  float r6 = fmaxf(acc[6], 0.f), r7 = fmaxf(acc[7], 0.f);
  o0.x = (unsigned)f2bf(r0) | ((unsigned)f2bf(r1) << 16);
  o0.y = (unsigned)f2bf(r2) | ((unsigned)f2bf(r3) << 16);
  o0.z = (unsigned)f2bf(r4) | ((unsigned)f2bf(r5) << 16);
  o0.w = (unsigned)f2bf(r6) | ((unsigned)f2bf(r7) << 16);
  float s0 = fmaxf(acc[8], 0.f), s1 = fmaxf(acc[9], 0.f);
  float s2 = fmaxf(acc[10], 0.f), s3 = fmaxf(acc[11], 0.f);
  float s4 = fmaxf(acc[12], 0.f), s5 = fmaxf(acc[13], 0.f);
  float s6 = fmaxf(acc[14], 0.f), s7 = fmaxf(acc[15], 0.f);
  o1.x = (unsigned)f2bf(s0) | ((unsigned)f2bf(s1) << 16);
  o1.y = (unsigned)f2bf(s2) | ((unsigned)f2bf(s3) << 16);
  o1.z = (unsigned)f2bf(s4) | ((unsigned)f2bf(s5) << 16);
  o1.w = (unsigned)f2bf(s6) | ((unsigned)f2bf(s7) << 16);
  uint4* op = reinterpret_cast<uint4*>(out + row * 64 + c * 16);
  op[0] = o0;
  op[1] = o1;
}

// ---------------- pooling (sorted-segment reduction) + head ----------------

__global__ __launch_bounds__(64) void graph_start_kernel(
    const int* __restrict__ batch, int* __restrict__ gstart) {
  int g = blockIdx.x * 64 + threadIdx.x;
  if (g > NG) return;
  int lo = 0, hi = NN;
  while (lo < hi) {
    int mid = (lo + hi) >> 1;
    if (batch[mid] < g)
      lo = mid + 1;
    else
      hi = mid;
  }
  gstart[g] = lo;
}

__global__ __launch_bounds__(64) void pool_head_kernel(
    const unsigned short* __restrict__ h2, const int* __restrict__ gstart,
    const float* __restrict__ Wo, const float* __restrict__ bo,
    float* __restrict__ out) {
  __shared__ float sm[64];
  int g = blockIdx.x;
  int c = threadIdx.x;
  int beg = gstart[g], end = gstart[g + 1];
  float acc = 0.f;
  for (int i = beg; i < end; ++i) acc += bf2f(h2[(size_t)i * 64 + c]);
  sm[c] = acc;
  __syncthreads();
  if (c < NO) {
    float o = bo[c];
#pragma unroll
    for (int k = 0; k < 64; ++k) o += sm[k] * Wo[k * 16 + c];
    out[g * 16 + c] = o;
  }
}

extern "C" void kernel_launch(void* const* d_in, const int* in_sizes, int n_in,
                              void* d_out, int out_size, void* d_ws,
                              size_t ws_size, hipStream_t stream) {
  const float* x = (const float*)d_in[0];
  const int* ei = (const int*)d_in[1];
  const int* batch = (const int*)d_in[2];
  const float* Wl1 = (const float*)d_in[3];
  const float* Wr1 = (const float*)d_in[4];
  const float* b1 = (const float*)d_in[5];
  const float* Wl2 = (const float*)d_in[6];
  const float* Wr2 = (const float*)d_in[7];
  const float* b2 = (const float*)d_in[8];
  const float* Wo = (const float*)d_in[9];
  const float* bo = (const float*)d_in[10];
  float* out = (float*)d_out;

  // Workspace: 16B-aligned big arrays first, then ints.
  unsigned short* x_bf = (unsigned short*)d_ws;      // NN*64 bf16 (6.4 MB)
  unsigned short* agg_bf = x_bf + (size_t)NN * 64;   // NN*64 bf16
  unsigned short* h1_bf = agg_bf + (size_t)NN * 64;  // NN*64 bf16
  int* col = (int*)(h1_bf + (size_t)NN * 64);        // NE
  int* row_ptr = col + NE;                           // NN+1
  int* cursor = row_ptr + NN + 1;                    // NN
  int* btot = cursor + NN;                           // KB
  int* bbase = btot + KB;                            // KB+1
  int* bcursor = bbase + KB + 1;                     // KB
  int* gstart = bcursor + KB;                        // NG+1
  // ebuf (NE uint32 = 4MB) aliases agg_bf (6.4MB): dead before gather
  // first writes agg_bf.
  unsigned int* ebuf = (unsigned int*)agg_bf;

  hipMemsetAsync(btot, 0, KB * sizeof(int), stream);

  const int eblocks = (NE + 255) / 256;
  const int gather_blocks = (NN * 8 + 255) / 256;
  const int gemm_blocks = (NN + 63) / 64;

  // x -> bf16 (independent of CSR build)
  cvt_f32_bf16<<<(NN * 64 / 8 + 255) / 256, 256, 0, stream>>>(x, x_bf,
                                                              NN * 64 / 8);

  // CSR build (once; reused by both layers) + graph segment bounds
  bucket_count<<<SBLK, 256, 0, stream>>>(ei, btot);
  scan_btot<<<1, 64, 0, stream>>>(btot, bbase, bcursor);
  bucket_scatter<<<SBLK, 256, 0, stream>>>(ei, bcursor, ebuf);
  bucket_rowptr<<<KB, 512, 0, stream>>>(ebuf, bbase, row_ptr, cursor);
  local_place<<<eblocks, 256, 0, stream>>>(ebuf, cursor, col);
  graph_start_kernel<<<(NG + 64) / 64, 64, 0, stream>>>(batch, gstart);

  // Layer 1
  gather_csr_bf<<<gather_blocks, 256, 0, stream>>>(x_bf, row_ptr, col, agg_bf);
  sage_lin_relu_bf<<<gemm_blocks, 256, 0, stream>>>(agg_bf, x_bf, Wl1, Wr1, b1,
                                                    h1_bf);

  // Layer 2 (h2 written in-place into agg_bf)
  gather_csr_bf<<<gather_blocks, 256, 0, stream>>>(h1_bf, row_ptr, col,
                                                   agg_bf);
  sage_lin_relu_bf<<<gemm_blocks, 256, 0, stream>>>(agg_bf, h1_bf, Wl2, Wr2,
                                                    b2, agg_bf);

  // Pool (segmented, no atomics) + head
  pool_head_kernel<<<NG, 64, 0, stream>>>(agg_bf, gstart, Wo, bo, out);
}